// Round 8
// baseline (646.679 us; speedup 1.0000x reference)
//
#include <hip/hip_runtime.h>

#define NN 20480
#define NPTS 81920   // B(4) * N(20480)
#define PS 260       // per-point plane stride (16k x 16ch + 4 pad)
#define MS 36        // mid/act row stride

__device__ __forceinline__ float redsum16(float v){
    v += __shfl_xor(v, 1); v += __shfl_xor(v, 2);
    v += __shfl_xor(v, 4); v += __shfl_xor(v, 8);
    return v;
}
__device__ __forceinline__ float redmax16(float v){
    v = fmaxf(v, __shfl_xor(v, 1)); v = fmaxf(v, __shfl_xor(v, 2));
    v = fmaxf(v, __shfl_xor(v, 4)); v = fmaxf(v, __shfl_xor(v, 8));
    return v;
}
// Wave-scope LDS producer->consumer fence (all phase dataflow is wave-local).
__device__ __forceinline__ void wsync(){
    __builtin_amdgcn_wave_barrier();
    __threadfence_block();
    __builtin_amdgcn_wave_barrier();
}

__global__ void k_fill4(float4* out, float val, int n4){
    int i = blockIdx.x * blockDim.x + threadIdx.x;
    int stride = gridDim.x * blockDim.x;
    float4 v = make_float4(val, val, val, val);
    for (; i < n4; i += stride) out[i] = v;
}

// f_pc = relu(g * (m1_W @ feature) + b), stored point-major (B,N,16) f32
__global__ __launch_bounds__(256) void k_feat0(
    const float* __restrict__ featp,
    const float* __restrict__ m1W,
    const float* __restrict__ m1g,
    const float* __restrict__ m1b,
    float* __restrict__ feat0)
{
    int p = blockIdx.x * 256 + threadIdx.x;
    if (p >= NPTS) return;
    int b = p / NN;
    int n = p - b * NN;
    float x[16];
    #pragma unroll
    for (int c = 0; c < 16; c++) x[c] = featp[(b*16 + c)*NN + n];
    float* dst = feat0 + (size_t)p * 16;
    for (int o = 0; o < 16; o++){          // rolled: small code
        float acc = 0.f;
        #pragma unroll
        for (int c = 0; c < 16; c++) acc = fmaf(m1W[o*16 + c], x[c], acc);
        dst[o] = fmaxf(fmaf(m1g[o], acc, m1b[o]), 0.f);
    }
}

// Phase B core: p?fc logits + ONLINE softmax + weighted pool (no index arrays).
// Lane owns channels o2 and o2+16 of one point pt.
__device__ __forceinline__ void phaseB(
    const float* __restrict__ fc, const float* sm, const float* fP,
    const float* lP, int gOff, int dOff, int pt, int o2, float* outA, float* outB)
{
    float wA[34], wB[34];
    const float2* a2 = (const float2*)(fc + o2*34);
    const float2* b2 = (const float2*)(fc + (o2+16)*34);
    #pragma unroll
    for (int i = 0; i < 17; i++){
        float2 t = a2[i]; wA[2*i] = t.x; wA[2*i+1] = t.y;
        float2 u = b2[i]; wB[2*i] = u.x; wB[2*i+1] = u.y;
    }
    float mA = -1e30f, sA = 0.f, nA = 0.f;
    float mB = -1e30f, sB = 0.f, nB = 0.f;
    for (int kk = 0; kk < 16; kk++){      // rolled
        float g = sm[gOff + pt*16 + kk];
        float d = sm[dOff + pt*16 + kk];
        float aA = fmaf(wA[1], d, wA[0]*g);
        float aB = fmaf(wB[1], d, wB[0]*g);
        const float* fr = fP + kk*16;
        const float* lr = lP + kk*16;
        #pragma unroll
        for (int v = 0; v < 4; v++){
            float4 F = ((const float4*)fr)[v];
            float4 L = ((const float4*)lr)[v];
            aA = fmaf(wA[2+4*v],  F.x, aA); aA = fmaf(wA[3+4*v],  F.y, aA);
            aA = fmaf(wA[4+4*v],  F.z, aA); aA = fmaf(wA[5+4*v],  F.w, aA);
            aA = fmaf(wA[18+4*v], L.x, aA); aA = fmaf(wA[19+4*v], L.y, aA);
            aA = fmaf(wA[20+4*v], L.z, aA); aA = fmaf(wA[21+4*v], L.w, aA);
            aB = fmaf(wB[2+4*v],  F.x, aB); aB = fmaf(wB[3+4*v],  F.y, aB);
            aB = fmaf(wB[4+4*v],  F.z, aB); aB = fmaf(wB[5+4*v],  F.w, aB);
            aB = fmaf(wB[18+4*v], L.x, aB); aB = fmaf(wB[19+4*v], L.y, aB);
            aB = fmaf(wB[20+4*v], L.z, aB); aB = fmaf(wB[21+4*v], L.w, aB);
        }
        float fval = fr[o2], lval = lr[o2];
        float mnA = fmaxf(mA, aA);
        float rA = __expf(mA - mnA), eA = __expf(aA - mnA);
        sA = fmaf(sA, rA, eA); nA = fmaf(nA, rA, eA * fval); mA = mnA;
        float mnB = fmaxf(mB, aB);
        float rB = __expf(mB - mnB), eB = __expf(aB - mnB);
        sB = fmaf(sB, rB, eB); nB = fmaf(nB, rB, eB * lval); mB = mnB;
    }
    *outA = nA / sA; *outB = nB / sB;
}

// ---------------- Stage 1 ----------------
// LDS floats: F=0(2080) L=2080(2080) G=4160(128) D=4288(128) MID=4416(288)
__global__ __launch_bounds__(128) void k_stage1(
    const float* __restrict__ xyzp,
    const int* __restrict__ nidx,
    const float* __restrict__ feat0,
    const float* __restrict__ lm1W,
    const float* __restrict__ lm1g,
    const float* __restrict__ lm1b,
    const float* __restrict__ p1fc,
    const float* __restrict__ p1mW,
    const float* __restrict__ p1mg,
    const float* __restrict__ p1mb,
    float* __restrict__ feat1)
{
    __shared__ float sm[4704];
    const int k  = threadIdx.x & 15;
    const int pt = threadIdx.x >> 4;
    const int p  = (blockIdx.x << 3) + pt;
    const int b  = p / NN;

    // ---- Phase A ----
    {
        const int ii = nidx[(p << 4) + k];
        const int q  = b * NN + ii;
        const float4* an = (const float4*)(feat0 + (size_t)q * 16);
        const float4* as = (const float4*)(feat0 + (size_t)p * 16);
        const float sx = xyzp[p*3 + 0];
        const float sy = xyzp[p*3 + 1];
        const float sz = xyzp[p*3 + 2];
        const float nx = xyzp[q*3 + 0];
        const float ny = xyzp[q*3 + 1];
        const float nz = xyzp[q*3 + 2];

        float* fRow = sm + pt*PS + k*16;
        float sd = 0.f;
        #pragma unroll
        for (int v = 0; v < 4; v++){
            float4 A = an[v]; float4 S = as[v];
            ((float4*)fRow)[v] = A;
            sd += fabsf(S.x-A.x) + fabsf(S.y-A.y) + fabsf(S.z-A.z) + fabsf(S.w-A.w);
        }
        sm[4288 + pt*16 + k] = 2.f * __expf(-sd * 0.0625f);   // LAMDA*f_dis

        float rx = sx - nx, ry = sy - ny, rz = sz - nz;
        float r2 = rx*rx + ry*ry;
        float rdis = sqrtf(r2 + rz*rz);
        float ralpha = atan2f(ry, rx);
        float rbeta  = atan2f(rz, sqrtf(r2));
        sm[4160 + pt*16 + k] = __expf(-rdis);                 // g_dis

        float mx = redsum16(nx) * 0.0625f;
        float my = redsum16(ny) * 0.0625f;
        float mz = redsum16(nz) * 0.0625f;
        float dx = sx - mx, dy = sy - my, dz = sz - mz;
        float dalpha = atan2f(dy, dx);
        float dbeta  = atan2f(dz, sqrtf(dx*dx + dy*dy));

        const float r0 = ralpha - dalpha, r1 = rbeta - dbeta;
        float* lRow = sm + 2080 + pt*PS + k*16;
        for (int o = 0; o < 16; o++){          // rolled
            const float* wr = lm1W + o*9;
            float acc =        wr[0]*r0;
            acc = fmaf(wr[1], r1,   acc); acc = fmaf(wr[2], rdis, acc);
            acc = fmaf(wr[3], sx,   acc); acc = fmaf(wr[4], sy,   acc);
            acc = fmaf(wr[5], sz,   acc); acc = fmaf(wr[6], nx,   acc);
            acc = fmaf(wr[7], ny,   acc); acc = fmaf(wr[8], nz,   acc);
            lRow[o] = fmaxf(fmaf(lm1g[o], acc, lm1b[o]), 0.f);
        }
    }
    wsync();

    // ---- Phase B ----
    {
        float oA, oB;
        phaseB(p1fc, sm, sm + pt*PS, sm + 2080 + pt*PS, 4160, 4288, pt, k, &oA, &oB);
        sm[4416 + pt*MS + k]      = oA;
        sm[4416 + pt*MS + k + 16] = oB;
    }
    wsync();

    // ---- Phase C : p1m row k (rolled, operands straight from LDS/global) ----
    {
        const float4* mp = (const float4*)(sm + 4416 + pt*MS);
        const float4* w4 = (const float4*)(p1mW + k*32);
        float acc = 0.f;
        for (int i = 0; i < 8; i++){
            float4 m = mp[i]; float4 w = w4[i];
            acc = fmaf(w.x, m.x, acc); acc = fmaf(w.y, m.y, acc);
            acc = fmaf(w.z, m.z, acc); acc = fmaf(w.w, m.w, acc);
        }
        feat1[(size_t)(p << 4) + k] = fmaxf(fmaf(p1mg[k], acc, p1mb[k]), 0.f);
    }
}

// ---------------- Stage 2 ----------------
// LDS floats: F=0(2080) L=2080(2080) G=4160(128) D=4288(128) LGR=4416(8)
//             MID=4424(288) ACT=4712(288)
__global__ __launch_bounds__(128) void k_stage2(
    const float* __restrict__ featp,
    const float* __restrict__ xyzp,
    const int* __restrict__ nidx,
    const float* __restrict__ feat1,
    const float* __restrict__ lm1W,
    const float* __restrict__ lm1g,
    const float* __restrict__ lm1b,
    const float* __restrict__ lm2W,
    const float* __restrict__ lm2g,
    const float* __restrict__ lm2b,
    const float* __restrict__ p2fc,
    const float* __restrict__ p2mW,
    const float* __restrict__ p2mg,
    const float* __restrict__ p2mb,
    const float* __restrict__ m2W,
    const float* __restrict__ m2g,
    const float* __restrict__ m2b,
    const float* __restrict__ scW,
    const float* __restrict__ scg,
    const float* __restrict__ scb,
    const float* __restrict__ m3W,
    const float* __restrict__ m3g,
    const float* __restrict__ m3b,
    const float* __restrict__ m4W,
    const float* __restrict__ m4g,
    const float* __restrict__ m4b,
    float* __restrict__ outp)
{
    __shared__ float sm[5000];
    const int k  = threadIdx.x & 15;
    const int pt = threadIdx.x >> 4;
    const int p  = (blockIdx.x << 3) + pt;
    const int b  = p / NN;
    const int n  = p - b * NN;

    // ---- Phase A ----
    {
        const int ii = nidx[(p << 4) + k];
        const int q  = b * NN + ii;
        const float4* an = (const float4*)(feat1 + (size_t)q * 16);
        const float4* as = (const float4*)(feat1 + (size_t)p * 16);
        const float sx = xyzp[p*3 + 0];
        const float sy = xyzp[p*3 + 1];
        const float sz = xyzp[p*3 + 2];
        const float nx = xyzp[q*3 + 0];
        const float ny = xyzp[q*3 + 1];
        const float nz = xyzp[q*3 + 2];

        float* fRow = sm + pt*PS + k*16;
        float sd = 0.f;
        #pragma unroll
        for (int v = 0; v < 4; v++){
            float4 A = an[v]; float4 S = as[v];
            ((float4*)fRow)[v] = A;
            sd += fabsf(S.x-A.x) + fabsf(S.y-A.y) + fabsf(S.z-A.z) + fabsf(S.w-A.w);
        }
        sm[4288 + pt*16 + k] = 2.f * __expf(-sd * 0.0625f);

        float rx = sx - nx, ry = sy - ny, rz = sz - nz;
        float r2 = rx*rx + ry*ry;
        float rdis = sqrtf(r2 + rz*rz);
        float ralpha = atan2f(ry, rx);
        float rbeta  = atan2f(rz, sqrtf(r2));
        sm[4160 + pt*16 + k] = __expf(-rdis);

        float mx = redsum16(nx) * 0.0625f;
        float my = redsum16(ny) * 0.0625f;
        float mz = redsum16(nz) * 0.0625f;
        float dx = sx - mx, dy = sy - my, dz = sz - mz;
        float dalpha = atan2f(dy, dx);
        float dbeta  = atan2f(dz, sqrtf(dx*dx + dy*dy));

        float mxd = redmax16(rdis);
        float nr  = sqrtf(sx*sx + sy*sy + sz*sz);
        if (k == 0) sm[4416 + pt] = (mxd*mxd*mxd) / (nr*nr*nr);   // lg_ratio

        // lm1 unrolled (lrep must stay a const-indexed register array)
        const float r0 = ralpha - dalpha, r1 = rbeta - dbeta;
        float rep[9] = { r0, r1, rdis, sx, sy, sz, nx, ny, nz };
        float lrep[16];
        #pragma unroll
        for (int o = 0; o < 16; o++){
            float acc = 0.f;
            #pragma unroll
            for (int c = 0; c < 9; c++) acc = fmaf(lm1W[o*9 + c], rep[c], acc);
            lrep[o] = fmaxf(fmaf(lm1g[o], acc, lm1b[o]), 0.f);
        }
        // lm2 rolled (writes to LDS, dynamic o fine)
        float* lRow = sm + 2080 + pt*PS + k*16;
        for (int o = 0; o < 16; o++){
            float acc = 0.f;
            #pragma unroll
            for (int c = 0; c < 16; c++) acc = fmaf(lm2W[o*16 + c], lrep[c], acc);
            lRow[o] = fmaxf(fmaf(lm2g[o], acc, lm2b[o]), 0.f);   // lrep2
        }
    }
    wsync();

    // ---- Phase B ----
    {
        float oA, oB;
        phaseB(p2fc, sm, sm + pt*PS, sm + 2080 + pt*PS, 4160, 4288, pt, k, &oA, &oB);
        sm[4424 + pt*MS + k]      = oA;
        sm[4424 + pt*MS + k + 16] = oB;
    }
    wsync();

    // ---- Phase C1 : p2m (relu) -> ACT (rolled) ----
    {
        const float4* mp = (const float4*)(sm + 4424 + pt*MS);
        const float4* wa = (const float4*)(p2mW + k*32);
        const float4* wb = (const float4*)(p2mW + (k+16)*32);
        float actA = 0.f, actB = 0.f;
        for (int i = 0; i < 8; i++){
            float4 m = mp[i]; float4 a = wa[i]; float4 c = wb[i];
            actA = fmaf(a.x, m.x, actA); actA = fmaf(a.y, m.y, actA);
            actA = fmaf(a.z, m.z, actA); actA = fmaf(a.w, m.w, actA);
            actB = fmaf(c.x, m.x, actB); actB = fmaf(c.y, m.y, actB);
            actB = fmaf(c.z, m.z, actB); actB = fmaf(c.w, m.w, actB);
        }
        sm[4712 + pt*MS + k]      = fmaxf(fmaf(p2mg[k],    actA, p2mb[k]),    0.f);
        sm[4712 + pt*MS + k + 16] = fmaxf(fmaf(p2mg[k+16], actB, p2mb[k+16]), 0.f);
    }
    wsync();

    // ---- Phase C2 : m2 + sc + m3 -> sH (aliases pt's F slice) ----
    {
        float hA[4] = {0.f, 0.f, 0.f, 0.f};
        {
            const float4* ap = (const float4*)(sm + 4712 + pt*MS);
            for (int i = 0; i < 8; i++){    // rolled
                float4 a = ap[i];
                #pragma unroll
                for (int j = 0; j < 4; j++){
                    float4 w = *(const float4*)(m2W + (k+16*j)*32 + 4*i);
                    hA[j] = fmaf(w.x, a.x, hA[j]); hA[j] = fmaf(w.y, a.y, hA[j]);
                    hA[j] = fmaf(w.z, a.z, hA[j]); hA[j] = fmaf(w.w, a.w, hA[j]);
                }
            }
        }
        float sA4[4] = {0.f, 0.f, 0.f, 0.f};
        for (int i = 0; i < 4; i++){        // rolled sc
            float x0 = featp[(b*16 + 4*i + 0)*NN + n];
            float x1 = featp[(b*16 + 4*i + 1)*NN + n];
            float x2 = featp[(b*16 + 4*i + 2)*NN + n];
            float x3 = featp[(b*16 + 4*i + 3)*NN + n];
            #pragma unroll
            for (int j = 0; j < 4; j++){
                float4 w = *(const float4*)(scW + (k+16*j)*16 + 4*i);
                sA4[j] = fmaf(w.x, x0, sA4[j]); sA4[j] = fmaf(w.y, x1, sA4[j]);
                sA4[j] = fmaf(w.z, x2, sA4[j]); sA4[j] = fmaf(w.w, x3, sA4[j]);
            }
        }
        const float sx = xyzp[p*3 + 0];
        const float sy = xyzp[p*3 + 1];
        const float sz = xyzp[p*3 + 2];
        const float lgr = sm[4416 + pt];
        float* sH = sm + pt*PS;     // F slice of this pt (dead after phase B)
        #pragma unroll
        for (int j = 0; j < 4; j++){
            int oo = k + 16*j;
            float scv = fmaf(scg[oo], sA4[j], scb[oo]);
            float m2v = fmaf(m2g[oo], hA[j],  m2b[oo]);
            float4 w3 = *(const float4*)(m3W + oo*4);
            float acc = w3.x * sx;
            acc = fmaf(w3.y, sy,  acc);
            acc = fmaf(w3.z, sz,  acc);
            acc = fmaf(w3.w, lgr, acc);
            sH[oo]      = m2v + scv;
            sH[64 + oo] = fmaf(m3g[oo], acc, m3b[oo]);
        }
    }
    wsync();

    // ---- Phase C3 : m4 (relu), rolled cb loop ----
    float o4[4] = {0.f, 0.f, 0.f, 0.f};
    {
        const float* hRow = sm + pt*PS;
        for (int cb = 0; cb < 32; cb++){    // rolled
            const float4 hv = *(const float4*)(hRow + cb*4);
            #pragma unroll
            for (int j = 0; j < 4; j++){
                const float4 wv = *(const float4*)(m4W + (k+16*j)*128 + cb*4);
                o4[j] = fmaf(wv.x, hv.x, o4[j]);
                o4[j] = fmaf(wv.y, hv.y, o4[j]);
                o4[j] = fmaf(wv.z, hv.z, o4[j]);
                o4[j] = fmaf(wv.w, hv.w, o4[j]);
            }
        }
    }
    wsync();   // sOut aliases wave's L half (dead after phase B)
    {
        const int w   = threadIdx.x >> 6;     // wave id (0/1)
        const int l   = threadIdx.x & 63;
        float* sOutW  = sm + 2080 + w*1040;   // 256 floats used
        const int pt3 = pt & 3;
        #pragma unroll
        for (int j = 0; j < 4; j++)
            sOutW[4*(k + 16*j) + pt3] = fmaxf(fmaf(m4g[k+16*j], o4[j], m4b[k+16*j]), 0.f);
        wsync();
        const int pbase = blockIdx.x << 3;
        const int b0 = pbase / NN;
        const int n0 = pbase - b0 * NN + 4*w;
        float4 u = *(const float4*)(sOutW + 4*l);
        *(float4*)(outp + (size_t)(b0*64 + l)*NN + n0) = u;
    }
}

extern "C" void kernel_launch(void* const* d_in, const int* in_sizes, int n_in,
                              void* d_out, int out_size, void* d_ws, size_t ws_size,
                              hipStream_t stream) {
    float* outp = (float*)d_out;

    // Deterministic contract check, encoded in fill value (capture-safe).
    float fillv = 1.0f;
    bool ok = true;
    if (n_in != 32) { fillv = 5.0f; ok = false; }
    else if (in_sizes[0] != 1310720 || in_sizes[1] != 245760 ||
             in_sizes[31] != 1310720) { fillv = 7.0f; ok = false; }
    else if (out_size != 5242880) { fillv = 9.0f; ok = false; }
    else if (ws_size < (size_t)2 * NPTS * 16 * sizeof(float)) { fillv = 11.0f; ok = false; }

    k_fill4<<<1024, 256, 0, stream>>>((float4*)outp, fillv, out_size/4);
    if (!ok) return;

    const float* featp = (const float*)d_in[0];
    const float* xyzp  = (const float*)d_in[1];
    const int*   nidx  = (const int*)d_in[31];

    float* feat0 = (float*)d_ws;                       // NPTS*16 f32
    float* feat1 = (float*)d_ws + (size_t)NPTS * 16;   // NPTS*16 f32

    #define W(i) ((const float*)d_in[2 + (i)])
    k_feat0<<<NPTS/256, 256, 0, stream>>>(featp, W(0), W(1), W(2), feat0);
    k_stage1<<<NPTS/8, 128, 0, stream>>>(xyzp, nidx, feat0,
        W(3), W(4), W(5), W(9), W(10), W(11), W(12), feat1);
    k_stage2<<<NPTS/8, 128, 0, stream>>>(featp, xyzp, nidx, feat1,
        W(3), W(4), W(5),          // lm1
        W(6), W(7), W(8),          // lm2
        W(13),                     // p2fc
        W(14), W(15), W(16),       // p2m
        W(17), W(18), W(19),       // m2
        W(20), W(21), W(22),       // sc
        W(23), W(24), W(25),       // m3
        W(26), W(27), W(28),       // m4
        outp);
    #undef W
}